// Round 7
// baseline (268.868 us; speedup 1.0000x reference)
//
#include <hip/hip_runtime.h>
#include <math.h>

// SIF node: x [T=256, H=256, W=256, C=3] fp32 -> out [256,256,3] fp32.
// Per pixel: sequential IF scan over T; out = pow(count/256, 1/2.2).
//
// Rounds 1/2/6 (scalar/float4-PF8/float4-PF32, 3-12 waves/CU) all tie at
// kernel ~72 us (2.8 TB/s): wave-level MLP is NOT the limit. Theory: the
// 1 KB-per-wave column walk at 768 KB t-stride defeats DRAM row locality
// (each channel sees fragments of many rows -> ~1 KB/tRC ~ 2.8 TB/s cap,
// matching measurement; harness fills stream contiguously at 6.8 TB/s).
//
// This version: 4 adjacent float4 columns per thread. Per t-step a wave
// issues 4 back-to-back unit-stride dwordx4 instrs = 4 KB CONTIGUOUS, so
// full DRAM rows arrive clustered. Rolling DEPTH=8 t-pipeline (32 loads in
// flight/wave, statically indexed -> VGPRs). 192 blocks x 64 thr; each CU
// needs only ~33 GB/s. Per-pixel t-order unchanged -> bit-exact.

#define T_STEPS 256
#define NPIX (256 * 256 * 3)
#define NV (NPIX / 4)   // 49152 float4 columns
#define PPT 4           // adjacent float4 columns per thread
#define DEPTH 8         // t-steps in flight

__device__ __forceinline__ void sif_step(float4& mem, float4& cnt, float4 v) {
    mem.x += v.x; mem.y += v.y; mem.z += v.z; mem.w += v.w;
    bool fx = mem.x > 1.0f, fy = mem.y > 1.0f, fz = mem.z > 1.0f, fw = mem.w > 1.0f;
    cnt.x += fx ? 1.0f : 0.0f; cnt.y += fy ? 1.0f : 0.0f;
    cnt.z += fz ? 1.0f : 0.0f; cnt.w += fw ? 1.0f : 0.0f;
    mem.x = fx ? 0.0f : mem.x; mem.y = fy ? 0.0f : mem.y;
    mem.z = fz ? 0.0f : mem.z; mem.w = fw ? 0.0f : mem.w;
}

__global__ __launch_bounds__(64) void sif_kernel(const float* __restrict__ x,
                                                 float* __restrict__ out) {
    const int base = blockIdx.x * (64 * PPT) + threadIdx.x;
    const float4* __restrict__ p = reinterpret_cast<const float4*>(x) + base;

    float4 mem[PPT], cnt[PPT];
#pragma unroll
    for (int j = 0; j < PPT; ++j) {
        mem[j] = make_float4(0.f, 0.f, 0.f, 0.f);
        cnt[j] = make_float4(0.f, 0.f, 0.f, 0.f);
    }

    float4 buf[DEPTH][PPT];  // statically indexed only -> stays in VGPRs

    // Prologue: t = 0..DEPTH-1, 4 KB contiguous per (wave, t).
#pragma unroll
    for (int d = 0; d < DEPTH; ++d)
#pragma unroll
        for (int j = 0; j < PPT; ++j)
            buf[d][j] = p[d * NV + j * 64];

    // Main: consume t, immediately reissue t+DEPTH (rolling pipeline).
    for (int tb = 0; tb < T_STEPS / DEPTH - 1; ++tb) {
#pragma unroll
        for (int d = 0; d < DEPTH; ++d) {
            const int tnext = tb * DEPTH + d + DEPTH;
#pragma unroll
            for (int j = 0; j < PPT; ++j) {
                float4 v = buf[d][j];
                buf[d][j] = p[tnext * NV + j * 64];
                sif_step(mem[j], cnt[j], v);
            }
        }
    }

    // Epilogue: last DEPTH t-steps, consume only.
#pragma unroll
    for (int d = 0; d < DEPTH; ++d)
#pragma unroll
        for (int j = 0; j < PPT; ++j)
            sif_step(mem[j], cnt[j], buf[d][j]);

    const float g = 1.0f / 2.2f;
    float4* o = reinterpret_cast<float4*>(out) + base;
#pragma unroll
    for (int j = 0; j < PPT; ++j) {
        float4 r;
        r.x = powf(cnt[j].x * (1.0f / 256.0f), g);
        r.y = powf(cnt[j].y * (1.0f / 256.0f), g);
        r.z = powf(cnt[j].z * (1.0f / 256.0f), g);
        r.w = powf(cnt[j].w * (1.0f / 256.0f), g);
        o[j * 64] = r;
    }
}

extern "C" void kernel_launch(void* const* d_in, const int* in_sizes, int n_in,
                              void* d_out, int out_size, void* d_ws, size_t ws_size,
                              hipStream_t stream) {
    const float* x = (const float*)d_in[0];
    float* out = (float*)d_out;

    const int threads = 64;
    const int blocks = NV / (threads * PPT);  // 192
    sif_kernel<<<blocks, threads, 0, stream>>>(x, out);
}